// Round 13
// baseline (71.792 us; speedup 1.0000x reference)
//
#include <hip/hip_runtime.h>
#include <hip/hip_bf16.h>

// ---------------------------------------------------------------------------
// STFT loss on MI355X (gfx950). 2 kernels, no fills, no spin.
//   k1 prep:  A (x,y signals, bf16) + B (twiddle*hann, bf16) in MFMA fragment
//             order ([tile][kstep][lane][8]) -> ws; zeroes completion counter.
//   k2 stft_main: R11-proven geometry (grid 2048, wave tile 16 frames x 16
//             bins, launch_bounds(256,8) -> 8 waves/SIMD, VGPR<=64);
//             Nyquist bin 512 fused; partials -> ws; the LAST-FINISHING block
//             (atomic counter, no spin) reduces 2048 partials -> d_out.
// loss = mean(|log xm - log ym| + |xm - ym|) over [4096 frames, 513 bins].
// ---------------------------------------------------------------------------

#define T_LEN    524288
#define WIN_OFF  384
#define EPSQ     1e-8f
#define INV_N    (1.0f / (4096.0f * 513.0f))
#define A2PI_1024 6.1359231515425647e-3f   // 2*pi/1024
#define A2PI_256  2.4543692606170259e-2f   // 2*pi/256
#define NBLK     2048                      // main grid size

typedef __attribute__((ext_vector_type(8))) __bf16 bf16x8;
typedef __attribute__((ext_vector_type(4))) float  f32x4;

union bfbits { __hip_bfloat16 hb; __bf16 b; unsigned short u; };
static __device__ __forceinline__ __bf16 f2bf(float f) {
    bfbits t; t.hb = __float2bfloat16(f); return t.b;
}

// ---------------------------------------------------------------------------
// prep: fragment-ordered operands (layout proven rounds 8-11).
// A: chunk (ft,kk) at [ft*8+kk]*512 elems; lane l holds
//    A[frame = ft*16 + (l&15)][tap = kk*32 + (l>>4)*8 + j], j=0..7.
// B: chunk (bt,kk); lane l holds B[bin = bt*16 + (l&15)][same tap].
// Wave i: [0,4096) -> A (sig=i>>11, ft=(i>>3)&255, kk=i&7);
//         [4096,4352) -> B (bt=(i-4096)>>3, kk=(i-4096)&7).  grid 1088 x 256.
// ---------------------------------------------------------------------------
__global__ void prep(const float* __restrict__ x, const float* __restrict__ y,
                     __bf16* __restrict__ xb, __bf16* __restrict__ yb,
                     __bf16* __restrict__ bre, __bf16* __restrict__ bim,
                     unsigned* __restrict__ counter)
{
    const int tid  = threadIdx.x;
    const int lane = tid & 63;
    const int wid  = blockIdx.x * 4 + (tid >> 6);

    if (blockIdx.x == 0 && tid == 0) *counter = 0u;   // reset each call

    if (wid < 4096) {
        const int sig = wid >> 11;
        const int chunk = wid & 2047;            // ft*8 + kk
        const int ft = chunk >> 3;
        const int kk = chunk & 7;
        const float* src = sig ? y : x;
        __bf16*      dst = sig ? yb : xb;
        const int frame = ft * 16 + (lane & 15);
        const int base  = frame * 128 + WIN_OFF + kk * 32 + (lane >> 4) * 8;
        bf16x8 v;
        if (base + 7 < T_LEN) {
            const float4 a0 = *(const float4*)(src + base);
            const float4 a1 = *(const float4*)(src + base + 4);
            v[0]=f2bf(a0.x); v[1]=f2bf(a0.y); v[2]=f2bf(a0.z); v[3]=f2bf(a0.w);
            v[4]=f2bf(a1.x); v[5]=f2bf(a1.y); v[6]=f2bf(a1.z); v[7]=f2bf(a1.w);
        } else {
            #pragma unroll
            for (int j = 0; j < 8; ++j) {
                const int idx = base + j;
                v[j] = f2bf(idx < T_LEN ? src[idx] : 0.f);
            }
        }
        *(bf16x8*)(dst + (size_t)chunk * 512 + lane * 8) = v;
    } else if (wid < 4096 + 256) {
        const int i  = wid - 4096;               // bt*8 + kk
        const int bt = i >> 3;
        const int kk = i & 7;
        const int bin = bt * 16 + (lane & 15);
        const int k0  = kk * 32 + (lane >> 4) * 8;
        bf16x8 vr, vi;
        #pragma unroll
        for (int j = 0; j < 8; ++j) {
            const int k = k0 + j;
            const float win = 0.5f - 0.5f * __cosf(A2PI_256 * (float)k);
            const int phase = ((WIN_OFF + k) * bin) & 1023;
            float s, c;
            __sincosf(-A2PI_1024 * (float)phase, &s, &c);
            vr[j] = f2bf(c * win);
            vi[j] = f2bf(s * win);
        }
        const size_t off = (size_t)i * 512 + lane * 8;
        *(bf16x8*)(bre + off) = vr;
        *(bf16x8*)(bim + off) = vi;
    }
}

// ---------------------------------------------------------------------------
// main: grid 2048 = 256 frame-tiles x 8 bin-blocks; 256 threads = 4 waves.
// Wave tile: 16 frames x 16 bins. 8 waves/SIMD resident (VGPR cap 64).
// ---------------------------------------------------------------------------
__launch_bounds__(256, 8)
__global__ void stft_main(const __bf16* __restrict__ xb, const __bf16* __restrict__ yb,
                          const __bf16* __restrict__ bre, const __bf16* __restrict__ bim,
                          const float* __restrict__ x, const float* __restrict__ y,
                          float* __restrict__ partials, unsigned* __restrict__ counter,
                          float* __restrict__ out)
{
    const int tid  = threadIdx.x;
    const int lane = tid & 63;
    const int wv   = tid >> 6;

    const int ft = blockIdx.x & 255;            // frame tile (16 frames)
    const int bt = (blockIdx.x >> 8) * 4 + wv;  // bin tile (16 bins)

    // fragment-ordered pointers: tile stride 4096 elems, kstep stride 512
    const __bf16* pax = xb  + (size_t)ft * 4096 + lane * 8;
    const __bf16* pay = yb  + (size_t)ft * 4096 + lane * 8;
    const __bf16* pbr = bre + (size_t)bt * 4096 + lane * 8;
    const __bf16* pbi = bim + (size_t)bt * 4096 + lane * 8;

    f32x4 axr = (f32x4)0.f, axi = (f32x4)0.f;
    f32x4 ayr = (f32x4)0.f, ayi = (f32x4)0.f;

    #pragma unroll 2
    for (int kk = 0; kk < 8; ++kk) {
        const int ko = kk * 512;
        const bf16x8 fax = *(const bf16x8*)(pax + ko);
        const bf16x8 fay = *(const bf16x8*)(pay + ko);
        const bf16x8 fbr = *(const bf16x8*)(pbr + ko);
        const bf16x8 fbi = *(const bf16x8*)(pbi + ko);

        axr = __builtin_amdgcn_mfma_f32_16x16x32_bf16(fax, fbr, axr, 0, 0, 0);
        axi = __builtin_amdgcn_mfma_f32_16x16x32_bf16(fax, fbi, axi, 0, 0, 0);
        ayr = __builtin_amdgcn_mfma_f32_16x16x32_bf16(fay, fbr, ayr, 0, 0, 0);
        ayi = __builtin_amdgcn_mfma_f32_16x16x32_bf16(fay, fbi, ayi, 0, 0, 0);
    }

    // ---------------- epilogue: MFMA-tile loss ------------------------------
    float sum = 0.f;
    #pragma unroll
    for (int r = 0; r < 4; ++r) {
        const float xr = axr[r], xi = axi[r];
        const float yr = ayr[r], yi = ayi[r];
        const float xm = sqrtf(fmaxf(xr * xr + xi * xi, EPSQ));
        const float ym = sqrtf(fmaxf(yr * yr + yi * yi, EPSQ));
        sum += fabsf(__logf(xm) - __logf(ym)) + fabsf(xm - ym);
    }

    // ---------------- Nyquist bin 512: 2 frames per block (waves 0,1) -------
    if (wv < 2) {
        float w4[4];
        #pragma unroll
        for (int j = 0; j < 4; ++j) {
            const int m = lane * 4 + j;
            const float win = 0.5f - 0.5f * __cosf(A2PI_256 * (float)m);
            w4[j] = (m & 1) ? -win : win;
        }
        const int frame = blockIdx.x * 2 + wv;          // 0..4095
        const int base  = frame * 128 + WIN_OFF + lane * 4;
        float xr, yr;
        if (frame < 4092) {                             // wave-uniform branch
            const float4 xv = *(const float4*)(x + base);
            const float4 yv = *(const float4*)(y + base);
            xr = xv.x * w4[0] + xv.y * w4[1] + xv.z * w4[2] + xv.w * w4[3];
            yr = yv.x * w4[0] + yv.y * w4[1] + yv.z * w4[2] + yv.w * w4[3];
        } else {                                        // zero-pad tail
            xr = 0.f; yr = 0.f;
            #pragma unroll
            for (int j = 0; j < 4; ++j) {
                const int idx = base + j;
                if (idx < T_LEN) {
                    xr = fmaf(x[idx], w4[j], xr);
                    yr = fmaf(y[idx], w4[j], yr);
                }
            }
        }
        #pragma unroll
        for (int off = 32; off > 0; off >>= 1) {
            xr += __shfl_xor(xr, off, 64);
            yr += __shfl_xor(yr, off, 64);
        }
        if (lane == 0) {
            const float xm = sqrtf(fmaxf(xr * xr, EPSQ));
            const float ym = sqrtf(fmaxf(yr * yr, EPSQ));
            sum += fabsf(__logf(xm) - __logf(ym)) + fabsf(xm - ym);
        }
    }

    // ---------------- block reduce -> partial -------------------------------
    #pragma unroll
    for (int off = 32; off > 0; off >>= 1)
        sum += __shfl_down(sum, off, 64);

    __shared__ float red_s[4];
    __shared__ bool  amLast;
    if (lane == 0) red_s[wv] = sum;
    __syncthreads();
    if (tid == 0) {
        const float p = red_s[0] + red_s[1] + red_s[2] + red_s[3];
        __hip_atomic_store(&partials[blockIdx.x], p,
                           __ATOMIC_RELEASE, __HIP_MEMORY_SCOPE_AGENT);
        const unsigned old = __hip_atomic_fetch_add(counter, 1u,
                           __ATOMIC_ACQ_REL, __HIP_MEMORY_SCOPE_AGENT);
        amLast = (old == NBLK - 1);
    }
    __syncthreads();

    // ---------------- last-finishing block: reduce 2048 -> d_out ------------
    if (amLast) {
        float s = 0.f;
        #pragma unroll
        for (int q = 0; q < 8; ++q)
            s += __hip_atomic_load(&partials[tid + q * 256],
                      __ATOMIC_RELAXED, __HIP_MEMORY_SCOPE_AGENT);
        #pragma unroll
        for (int off = 32; off > 0; off >>= 1)
            s += __shfl_down(s, off, 64);
        if (lane == 0) red_s[wv] = s;
        __syncthreads();
        if (tid == 0)
            out[0] = (red_s[0] + red_s[1] + red_s[2] + red_s[3]) * INV_N;
    }
}

extern "C" void kernel_launch(void* const* d_in, const int* in_sizes, int n_in,
                              void* d_out, int out_size, void* d_ws, size_t ws_size,
                              hipStream_t stream) {
    const float* input  = (const float*)d_in[0];
    const float* target = (const float*)d_in[1];
    const float* x = input  + (size_t)7 * T_LEN;   // reference uses x_stft[-1]
    const float* y = target + (size_t)7 * T_LEN;

    // ws layout (bytes): bre[256K] bim[256K] xb[2M] yb[2M] partials[8K] ctr[4]
    char* ws = (char*)d_ws;
    __bf16*   wsBre  = (__bf16*)(ws);
    __bf16*   wsBim  = (__bf16*)(ws + 262144);
    __bf16*   wsXb   = (__bf16*)(ws + 524288);
    __bf16*   wsYb   = (__bf16*)(ws + 524288 + 2097152);
    float*    wsPart = (float*) (ws + 524288 + 4194304);
    unsigned* wsCtr  = (unsigned*)(ws + 524288 + 4194304 + 8192);

    prep<<<1088, 256, 0, stream>>>(x, y, wsXb, wsYb, wsBre, wsBim, wsCtr);
    stft_main<<<NBLK, 256, 0, stream>>>(wsXb, wsYb, wsBre, wsBim, x, y,
                                        wsPart, wsCtr, (float*)d_out);
}

// Round 14
// 25.614 us; speedup vs baseline: 2.8028x; 2.8028x over previous
//
#include <hip/hip_runtime.h>
#include <hip/hip_bf16.h>

// ---------------------------------------------------------------------------
// STFT loss on MI355X (gfx950). 3 kernels, no fills, no atomics (R11 structure
// + XCD-aware block mapping in stft_main).
//   k1 prep:  A (x,y signals, bf16) + B (twiddle*hann, bf16) in MFMA fragment
//             order ([tile][kstep][lane][8]) -> ws.
//   k2 stft_main: grid 2048, wave tile 16 frames x 16 bins, 8 waves/SIMD
//             (launch_bounds(256,8)); binblk = blockIdx&7 so default
//             round-robin dispatch pins one bin-block per XCD (A 4MB + B
//             slice 128KB fits the 4MB per-XCD L2); Nyquist fused; partials.
//   k3 reduce_partials: 2048 partials -> d_out (overwrite, no memset).
// loss = mean(|log xm - log ym| + |xm - ym|) over [4096 frames, 513 bins].
// ---------------------------------------------------------------------------

#define T_LEN    524288
#define WIN_OFF  384
#define EPSQ     1e-8f
#define INV_N    (1.0f / (4096.0f * 513.0f))
#define A2PI_1024 6.1359231515425647e-3f   // 2*pi/1024
#define A2PI_256  2.4543692606170259e-2f   // 2*pi/256
#define NBLK     2048                      // main grid size

typedef __attribute__((ext_vector_type(8))) __bf16 bf16x8;
typedef __attribute__((ext_vector_type(4))) float  f32x4;

union bfbits { __hip_bfloat16 hb; __bf16 b; unsigned short u; };
static __device__ __forceinline__ __bf16 f2bf(float f) {
    bfbits t; t.hb = __float2bfloat16(f); return t.b;
}

// ---------------------------------------------------------------------------
// prep: fragment-ordered operands (layout proven rounds 8-11).
// A: chunk (ft,kk) at [ft*8+kk]*512 elems; lane l holds
//    A[frame = ft*16 + (l&15)][tap = kk*32 + (l>>4)*8 + j], j=0..7.
// B: chunk (bt,kk); lane l holds B[bin = bt*16 + (l&15)][same tap].
// Wave i: [0,4096) -> A (sig=i>>11, ft=(i>>3)&255, kk=i&7);
//         [4096,4352) -> B (bt=(i-4096)>>3, kk=(i-4096)&7).  grid 1088 x 256.
// ---------------------------------------------------------------------------
__global__ void prep(const float* __restrict__ x, const float* __restrict__ y,
                     __bf16* __restrict__ xb, __bf16* __restrict__ yb,
                     __bf16* __restrict__ bre, __bf16* __restrict__ bim)
{
    const int tid  = threadIdx.x;
    const int lane = tid & 63;
    const int wid  = blockIdx.x * 4 + (tid >> 6);

    if (wid < 4096) {
        const int sig = wid >> 11;
        const int chunk = wid & 2047;            // ft*8 + kk
        const int ft = chunk >> 3;
        const int kk = chunk & 7;
        const float* src = sig ? y : x;
        __bf16*      dst = sig ? yb : xb;
        const int frame = ft * 16 + (lane & 15);
        const int base  = frame * 128 + WIN_OFF + kk * 32 + (lane >> 4) * 8;
        bf16x8 v;
        if (base + 7 < T_LEN) {
            const float4 a0 = *(const float4*)(src + base);
            const float4 a1 = *(const float4*)(src + base + 4);
            v[0]=f2bf(a0.x); v[1]=f2bf(a0.y); v[2]=f2bf(a0.z); v[3]=f2bf(a0.w);
            v[4]=f2bf(a1.x); v[5]=f2bf(a1.y); v[6]=f2bf(a1.z); v[7]=f2bf(a1.w);
        } else {
            #pragma unroll
            for (int j = 0; j < 8; ++j) {
                const int idx = base + j;
                v[j] = f2bf(idx < T_LEN ? src[idx] : 0.f);
            }
        }
        *(bf16x8*)(dst + (size_t)chunk * 512 + lane * 8) = v;
    } else if (wid < 4096 + 256) {
        const int i  = wid - 4096;               // bt*8 + kk
        const int bt = i >> 3;
        const int kk = i & 7;
        const int bin = bt * 16 + (lane & 15);
        const int k0  = kk * 32 + (lane >> 4) * 8;
        bf16x8 vr, vi;
        #pragma unroll
        for (int j = 0; j < 8; ++j) {
            const int k = k0 + j;
            const float win = 0.5f - 0.5f * __cosf(A2PI_256 * (float)k);
            const int phase = ((WIN_OFF + k) * bin) & 1023;
            float s, c;
            __sincosf(-A2PI_1024 * (float)phase, &s, &c);
            vr[j] = f2bf(c * win);
            vi[j] = f2bf(s * win);
        }
        const size_t off = (size_t)i * 512 + lane * 8;
        *(bf16x8*)(bre + off) = vr;
        *(bf16x8*)(bim + off) = vi;
    }
}

// ---------------------------------------------------------------------------
// main: grid 2048; binblk = blockIdx & 7 (one bin-block per XCD under default
// round-robin dispatch), ft = blockIdx >> 3. 256 threads = 4 waves.
// Wave tile: 16 frames x 16 bins. 8 waves/SIMD resident (VGPR cap 64).
// ---------------------------------------------------------------------------
__launch_bounds__(256, 8)
__global__ void stft_main(const __bf16* __restrict__ xb, const __bf16* __restrict__ yb,
                          const __bf16* __restrict__ bre, const __bf16* __restrict__ bim,
                          const float* __restrict__ x, const float* __restrict__ y,
                          float* __restrict__ partials)
{
    const int tid  = threadIdx.x;
    const int lane = tid & 63;
    const int wv   = tid >> 6;

    const int ft = blockIdx.x >> 3;             // frame tile (16 frames)
    const int bt = (blockIdx.x & 7) * 4 + wv;   // bin tile (16 bins), XCD-local

    // fragment-ordered pointers: tile stride 4096 elems, kstep stride 512
    const __bf16* pax = xb  + (size_t)ft * 4096 + lane * 8;
    const __bf16* pay = yb  + (size_t)ft * 4096 + lane * 8;
    const __bf16* pbr = bre + (size_t)bt * 4096 + lane * 8;
    const __bf16* pbi = bim + (size_t)bt * 4096 + lane * 8;

    f32x4 axr = (f32x4)0.f, axi = (f32x4)0.f;
    f32x4 ayr = (f32x4)0.f, ayi = (f32x4)0.f;

    #pragma unroll 2
    for (int kk = 0; kk < 8; ++kk) {
        const int ko = kk * 512;
        const bf16x8 fax = *(const bf16x8*)(pax + ko);
        const bf16x8 fay = *(const bf16x8*)(pay + ko);
        const bf16x8 fbr = *(const bf16x8*)(pbr + ko);
        const bf16x8 fbi = *(const bf16x8*)(pbi + ko);

        axr = __builtin_amdgcn_mfma_f32_16x16x32_bf16(fax, fbr, axr, 0, 0, 0);
        axi = __builtin_amdgcn_mfma_f32_16x16x32_bf16(fax, fbi, axi, 0, 0, 0);
        ayr = __builtin_amdgcn_mfma_f32_16x16x32_bf16(fay, fbr, ayr, 0, 0, 0);
        ayi = __builtin_amdgcn_mfma_f32_16x16x32_bf16(fay, fbi, ayi, 0, 0, 0);
    }

    // ---------------- epilogue: MFMA-tile loss ------------------------------
    float sum = 0.f;
    #pragma unroll
    for (int r = 0; r < 4; ++r) {
        const float xr = axr[r], xi = axi[r];
        const float yr = ayr[r], yi = ayi[r];
        const float xm = sqrtf(fmaxf(xr * xr + xi * xi, EPSQ));
        const float ym = sqrtf(fmaxf(yr * yr + yi * yi, EPSQ));
        sum += fabsf(__logf(xm) - __logf(ym)) + fabsf(xm - ym);
    }

    // ---------------- Nyquist bin 512: 2 frames per block (waves 0,1) -------
    if (wv < 2) {
        float w4[4];
        #pragma unroll
        for (int j = 0; j < 4; ++j) {
            const int m = lane * 4 + j;
            const float win = 0.5f - 0.5f * __cosf(A2PI_256 * (float)m);
            w4[j] = (m & 1) ? -win : win;
        }
        const int frame = blockIdx.x * 2 + wv;          // 0..4095
        const int base  = frame * 128 + WIN_OFF + lane * 4;
        float xr, yr;
        if (frame < 4092) {                             // wave-uniform branch
            const float4 xv = *(const float4*)(x + base);
            const float4 yv = *(const float4*)(y + base);
            xr = xv.x * w4[0] + xv.y * w4[1] + xv.z * w4[2] + xv.w * w4[3];
            yr = yv.x * w4[0] + yv.y * w4[1] + yv.z * w4[2] + yv.w * w4[3];
        } else {                                        // zero-pad tail
            xr = 0.f; yr = 0.f;
            #pragma unroll
            for (int j = 0; j < 4; ++j) {
                const int idx = base + j;
                if (idx < T_LEN) {
                    xr = fmaf(x[idx], w4[j], xr);
                    yr = fmaf(y[idx], w4[j], yr);
                }
            }
        }
        #pragma unroll
        for (int off = 32; off > 0; off >>= 1) {
            xr += __shfl_xor(xr, off, 64);
            yr += __shfl_xor(yr, off, 64);
        }
        if (lane == 0) {
            const float xm = sqrtf(fmaxf(xr * xr, EPSQ));
            const float ym = sqrtf(fmaxf(yr * yr, EPSQ));
            sum += fabsf(__logf(xm) - __logf(ym)) + fabsf(xm - ym);
        }
    }

    // ---------------- block reduce -> partial -------------------------------
    #pragma unroll
    for (int off = 32; off > 0; off >>= 1)
        sum += __shfl_down(sum, off, 64);

    __shared__ float red_s[4];
    if (lane == 0) red_s[wv] = sum;
    __syncthreads();
    if (tid == 0)
        partials[blockIdx.x] = red_s[0] + red_s[1] + red_s[2] + red_s[3];
}

// ---- final reduction: 2048 partials -> scalar (overwrites d_out) -----------
__global__ void reduce_partials(const float* __restrict__ partials,
                                float* __restrict__ out)
{
    const int tid = threadIdx.x;
    float s = 0.f;
    #pragma unroll
    for (int q = 0; q < 8; ++q)
        s += partials[tid + q * 256];
    #pragma unroll
    for (int off = 32; off > 0; off >>= 1)
        s += __shfl_down(s, off, 64);

    __shared__ float red[4];
    if ((tid & 63) == 0) red[tid >> 6] = s;
    __syncthreads();
    if (tid == 0)
        out[0] = (red[0] + red[1] + red[2] + red[3]) * INV_N;
}

extern "C" void kernel_launch(void* const* d_in, const int* in_sizes, int n_in,
                              void* d_out, int out_size, void* d_ws, size_t ws_size,
                              hipStream_t stream) {
    const float* input  = (const float*)d_in[0];
    const float* target = (const float*)d_in[1];
    const float* x = input  + (size_t)7 * T_LEN;   // reference uses x_stft[-1]
    const float* y = target + (size_t)7 * T_LEN;

    // ws layout (bytes): bre[256K] bim[256K] xb[2M] yb[2M] partials[8K]
    char* ws = (char*)d_ws;
    __bf16* wsBre  = (__bf16*)(ws);
    __bf16* wsBim  = (__bf16*)(ws + 262144);
    __bf16* wsXb   = (__bf16*)(ws + 524288);
    __bf16* wsYb   = (__bf16*)(ws + 524288 + 2097152);
    float*  wsPart = (float*) (ws + 524288 + 4194304);

    prep<<<1088, 256, 0, stream>>>(x, y, wsXb, wsYb, wsBre, wsBim);
    stft_main<<<NBLK, 256, 0, stream>>>(wsXb, wsYb, wsBre, wsBim, x, y, wsPart);
    reduce_partials<<<1, 256, 0, stream>>>(wsPart, (float*)d_out);
}

// Round 15
// 22.412 us; speedup vs baseline: 3.2032x; 1.1429x over previous
//
#include <hip/hip_runtime.h>
#include <hip/hip_bf16.h>

// ---------------------------------------------------------------------------
// STFT loss on MI355X (gfx950). 3 kernels, no fills, no atomics.
// == R11 configuration (best measured: 22.5 us), restored verbatim ==
//   k1 prep:  A (x,y signals, bf16) + B (twiddle*hann, bf16) in MFMA fragment
//             order ([tile][kstep][lane][8]) -> ws.
//   k2 stft_main: grid 2048, wave tile 16 frames x 16 bins, 8 waves/SIMD
//             (launch_bounds(256,8), VGPR<=64); 4 coalesced loads -> 4 MFMAs
//             per k-step; Nyquist bin 512 fused (waves 0-1); partials -> ws.
//   k3 reduce_partials: 2048 partials -> d_out (overwrite, no memset).
// loss = mean(|log xm - log ym| + |xm - ym|) over [4096 frames, 513 bins].
// ---------------------------------------------------------------------------

#define T_LEN    524288
#define WIN_OFF  384
#define EPSQ     1e-8f
#define INV_N    (1.0f / (4096.0f * 513.0f))
#define A2PI_1024 6.1359231515425647e-3f   // 2*pi/1024
#define A2PI_256  2.4543692606170259e-2f   // 2*pi/256
#define NBLK     2048                      // main grid size

typedef __attribute__((ext_vector_type(8))) __bf16 bf16x8;
typedef __attribute__((ext_vector_type(4))) float  f32x4;

union bfbits { __hip_bfloat16 hb; __bf16 b; unsigned short u; };
static __device__ __forceinline__ __bf16 f2bf(float f) {
    bfbits t; t.hb = __float2bfloat16(f); return t.b;
}

// ---------------------------------------------------------------------------
// prep: fragment-ordered operands (layout proven rounds 8-11).
// A: chunk (ft,kk) at [ft*8+kk]*512 elems; lane l holds
//    A[frame = ft*16 + (l&15)][tap = kk*32 + (l>>4)*8 + j], j=0..7.
// B: chunk (bt,kk); lane l holds B[bin = bt*16 + (l&15)][same tap].
// Wave i: [0,4096) -> A (sig=i>>11, ft=(i>>3)&255, kk=i&7);
//         [4096,4352) -> B (bt=(i-4096)>>3, kk=(i-4096)&7).  grid 1088 x 256.
// ---------------------------------------------------------------------------
__global__ void prep(const float* __restrict__ x, const float* __restrict__ y,
                     __bf16* __restrict__ xb, __bf16* __restrict__ yb,
                     __bf16* __restrict__ bre, __bf16* __restrict__ bim)
{
    const int tid  = threadIdx.x;
    const int lane = tid & 63;
    const int wid  = blockIdx.x * 4 + (tid >> 6);

    if (wid < 4096) {
        const int sig = wid >> 11;
        const int chunk = wid & 2047;            // ft*8 + kk
        const int ft = chunk >> 3;
        const int kk = chunk & 7;
        const float* src = sig ? y : x;
        __bf16*      dst = sig ? yb : xb;
        const int frame = ft * 16 + (lane & 15);
        const int base  = frame * 128 + WIN_OFF + kk * 32 + (lane >> 4) * 8;
        bf16x8 v;
        if (base + 7 < T_LEN) {
            const float4 a0 = *(const float4*)(src + base);
            const float4 a1 = *(const float4*)(src + base + 4);
            v[0]=f2bf(a0.x); v[1]=f2bf(a0.y); v[2]=f2bf(a0.z); v[3]=f2bf(a0.w);
            v[4]=f2bf(a1.x); v[5]=f2bf(a1.y); v[6]=f2bf(a1.z); v[7]=f2bf(a1.w);
        } else {
            #pragma unroll
            for (int j = 0; j < 8; ++j) {
                const int idx = base + j;
                v[j] = f2bf(idx < T_LEN ? src[idx] : 0.f);
            }
        }
        *(bf16x8*)(dst + (size_t)chunk * 512 + lane * 8) = v;
    } else if (wid < 4096 + 256) {
        const int i  = wid - 4096;               // bt*8 + kk
        const int bt = i >> 3;
        const int kk = i & 7;
        const int bin = bt * 16 + (lane & 15);
        const int k0  = kk * 32 + (lane >> 4) * 8;
        bf16x8 vr, vi;
        #pragma unroll
        for (int j = 0; j < 8; ++j) {
            const int k = k0 + j;
            const float win = 0.5f - 0.5f * __cosf(A2PI_256 * (float)k);
            const int phase = ((WIN_OFF + k) * bin) & 1023;
            float s, c;
            __sincosf(-A2PI_1024 * (float)phase, &s, &c);
            vr[j] = f2bf(c * win);
            vi[j] = f2bf(s * win);
        }
        const size_t off = (size_t)i * 512 + lane * 8;
        *(bf16x8*)(bre + off) = vr;
        *(bf16x8*)(bim + off) = vi;
    }
}

// ---------------------------------------------------------------------------
// main: grid 2048 = 256 frame-tiles x 8 bin-blocks; 256 threads = 4 waves.
// Wave tile: 16 frames x 16 bins (wave wv owns bin-tile (blockIdx>>8)*4+wv).
// The 4 waves share the same A fragments (L1 hits). 8 waves/SIMD resident.
// ---------------------------------------------------------------------------
__launch_bounds__(256, 8)
__global__ void stft_main(const __bf16* __restrict__ xb, const __bf16* __restrict__ yb,
                          const __bf16* __restrict__ bre, const __bf16* __restrict__ bim,
                          const float* __restrict__ x, const float* __restrict__ y,
                          float* __restrict__ partials)
{
    const int tid  = threadIdx.x;
    const int lane = tid & 63;
    const int wv   = tid >> 6;

    const int ft = blockIdx.x & 255;            // frame tile (16 frames)
    const int bt = (blockIdx.x >> 8) * 4 + wv;  // bin tile (16 bins)

    // fragment-ordered pointers: tile stride 4096 elems, kstep stride 512
    const __bf16* pax = xb  + (size_t)ft * 4096 + lane * 8;
    const __bf16* pay = yb  + (size_t)ft * 4096 + lane * 8;
    const __bf16* pbr = bre + (size_t)bt * 4096 + lane * 8;
    const __bf16* pbi = bim + (size_t)bt * 4096 + lane * 8;

    f32x4 axr = (f32x4)0.f, axi = (f32x4)0.f;
    f32x4 ayr = (f32x4)0.f, ayi = (f32x4)0.f;

    #pragma unroll 2
    for (int kk = 0; kk < 8; ++kk) {
        const int ko = kk * 512;
        const bf16x8 fax = *(const bf16x8*)(pax + ko);
        const bf16x8 fay = *(const bf16x8*)(pay + ko);
        const bf16x8 fbr = *(const bf16x8*)(pbr + ko);
        const bf16x8 fbi = *(const bf16x8*)(pbi + ko);

        axr = __builtin_amdgcn_mfma_f32_16x16x32_bf16(fax, fbr, axr, 0, 0, 0);
        axi = __builtin_amdgcn_mfma_f32_16x16x32_bf16(fax, fbi, axi, 0, 0, 0);
        ayr = __builtin_amdgcn_mfma_f32_16x16x32_bf16(fay, fbr, ayr, 0, 0, 0);
        ayi = __builtin_amdgcn_mfma_f32_16x16x32_bf16(fay, fbi, ayi, 0, 0, 0);
    }

    // ---------------- epilogue: MFMA-tile loss ------------------------------
    float sum = 0.f;
    #pragma unroll
    for (int r = 0; r < 4; ++r) {
        const float xr = axr[r], xi = axi[r];
        const float yr = ayr[r], yi = ayi[r];
        const float xm = sqrtf(fmaxf(xr * xr + xi * xi, EPSQ));
        const float ym = sqrtf(fmaxf(yr * yr + yi * yi, EPSQ));
        sum += fabsf(__logf(xm) - __logf(ym)) + fabsf(xm - ym);
    }

    // ---------------- Nyquist bin 512: 2 frames per block (waves 0,1) -------
    if (wv < 2) {
        float w4[4];
        #pragma unroll
        for (int j = 0; j < 4; ++j) {
            const int m = lane * 4 + j;
            const float win = 0.5f - 0.5f * __cosf(A2PI_256 * (float)m);
            w4[j] = (m & 1) ? -win : win;
        }
        const int frame = blockIdx.x * 2 + wv;          // 0..4095
        const int base  = frame * 128 + WIN_OFF + lane * 4;
        float xr, yr;
        if (frame < 4092) {                             // wave-uniform branch
            const float4 xv = *(const float4*)(x + base);
            const float4 yv = *(const float4*)(y + base);
            xr = xv.x * w4[0] + xv.y * w4[1] + xv.z * w4[2] + xv.w * w4[3];
            yr = yv.x * w4[0] + yv.y * w4[1] + yv.z * w4[2] + yv.w * w4[3];
        } else {                                        // zero-pad tail
            xr = 0.f; yr = 0.f;
            #pragma unroll
            for (int j = 0; j < 4; ++j) {
                const int idx = base + j;
                if (idx < T_LEN) {
                    xr = fmaf(x[idx], w4[j], xr);
                    yr = fmaf(y[idx], w4[j], yr);
                }
            }
        }
        #pragma unroll
        for (int off = 32; off > 0; off >>= 1) {
            xr += __shfl_xor(xr, off, 64);
            yr += __shfl_xor(yr, off, 64);
        }
        if (lane == 0) {
            const float xm = sqrtf(fmaxf(xr * xr, EPSQ));
            const float ym = sqrtf(fmaxf(yr * yr, EPSQ));
            sum += fabsf(__logf(xm) - __logf(ym)) + fabsf(xm - ym);
        }
    }

    // ---------------- block reduce -> partial -------------------------------
    #pragma unroll
    for (int off = 32; off > 0; off >>= 1)
        sum += __shfl_down(sum, off, 64);

    __shared__ float red_s[4];
    if (lane == 0) red_s[wv] = sum;
    __syncthreads();
    if (tid == 0)
        partials[blockIdx.x] = red_s[0] + red_s[1] + red_s[2] + red_s[3];
}

// ---- final reduction: 2048 partials -> scalar (overwrites d_out) -----------
__global__ void reduce_partials(const float* __restrict__ partials,
                                float* __restrict__ out)
{
    const int tid = threadIdx.x;
    float s = 0.f;
    #pragma unroll
    for (int q = 0; q < 8; ++q)
        s += partials[tid + q * 256];
    #pragma unroll
    for (int off = 32; off > 0; off >>= 1)
        s += __shfl_down(s, off, 64);

    __shared__ float red[4];
    if ((tid & 63) == 0) red[tid >> 6] = s;
    __syncthreads();
    if (tid == 0)
        out[0] = (red[0] + red[1] + red[2] + red[3]) * INV_N;
}

extern "C" void kernel_launch(void* const* d_in, const int* in_sizes, int n_in,
                              void* d_out, int out_size, void* d_ws, size_t ws_size,
                              hipStream_t stream) {
    const float* input  = (const float*)d_in[0];
    const float* target = (const float*)d_in[1];
    const float* x = input  + (size_t)7 * T_LEN;   // reference uses x_stft[-1]
    const float* y = target + (size_t)7 * T_LEN;

    // ws layout (bytes): bre[256K] bim[256K] xb[2M] yb[2M] partials[8K]
    char* ws = (char*)d_ws;
    __bf16* wsBre  = (__bf16*)(ws);
    __bf16* wsBim  = (__bf16*)(ws + 262144);
    __bf16* wsXb   = (__bf16*)(ws + 524288);
    __bf16* wsYb   = (__bf16*)(ws + 524288 + 2097152);
    float*  wsPart = (float*) (ws + 524288 + 4194304);

    prep<<<1088, 256, 0, stream>>>(x, y, wsXb, wsYb, wsBre, wsBim);
    stft_main<<<NBLK, 256, 0, stream>>>(wsXb, wsYb, wsBre, wsBim, x, y, wsPart);
    reduce_partials<<<1, 256, 0, stream>>>(wsPart, (float*)d_out);
}